// Round 10
// baseline (276.604 us; speedup 1.0000x reference)
//
#include <hip/hip_runtime.h>
#include <hip/hip_bf16.h>

// MDTA: [convert+transpose fused] -> qkv 1x1 conv (MFMA) -> 3x3 depthwise ->
// l2norm(q)+K^T materialize -> flash attention (R6-form P-via-LDS, 512 thr,
// in-block key-split, LDS half-combine) -> 1x1 proj (MFMA).
// LESSON (R7-R9): the "S^T register-P" inner form makes the allocator pin
// VGPRs at ~56 and spill 200-450 MB to scratch regardless of launch bounds.
// The R6 P-via-LDS form allocates ~104 and writes 3 MB. Keep the R6 form.

#define BB 2
#define CCH 192
#define C3 576
#define NH 4
#define HD 48
#define NP 4096

typedef __hip_bfloat16 bf16;
typedef __attribute__((ext_vector_type(8))) short bf16x8;
typedef __attribute__((ext_vector_type(4))) float f32x4;

union I4B8 { int4 i; bf16x8 v; };

__device__ inline float bf2f(bf16 v){ return __bfloat162float(v); }
__device__ inline unsigned short bfbits(bf16 v){ return __builtin_bit_cast(unsigned short, v); }
__device__ inline unsigned short f2bfbits(float f){ return __builtin_bit_cast(unsigned short, __float2bfloat16(f)); }
__device__ inline float bfb2f(short s){ return __uint_as_float(((unsigned)(unsigned short)s)<<16); }
__device__ inline unsigned pk2(float a, float b){
  return (unsigned)f2bfbits(a) | ((unsigned)f2bfbits(b)<<16);
}

// Inline dtype probe: bf16 data -> low short of dwords has sane exponent.
__device__ inline bool probe64(const void* x){
  unsigned u = ((const unsigned*)x)[threadIdx.x & 63];
  int e = (u >> 7) & 0xff;
  int sane = (e >= 100 && e <= 140) || ((u & 0x7fffu) == 0u);
  unsigned long long m = __ballot(sane);
  return __popcll(m) >= 48;
}

// ---------------------------------------------------------------------------
// Fused: blocks 0..383 transpose X -> XT [b][4096][192] bf16; blocks
// 384..985 convert params to canonical bf16.
// ---------------------------------------------------------------------------
#define NCANON 153988
__global__ __launch_bounds__(256) void pre_kernel(
    const void* __restrict__ Xv,
    const void* w_qkv, const void* b_qkv, const void* w_dw, const void* b_dw,
    const void* w_proj, const void* b_proj, const void* temp,
    bf16* __restrict__ canon, short* __restrict__ XT)
{
  const bool isbf = probe64(Xv);
  const int blk = blockIdx.x;
  if (blk < 384){
    __shared__ short T[64][66];
    const int c0 = (blk % 3)*64, p0 = ((blk/3) % 64)*64, b = blk/192;
    const size_t xbase = (size_t)b*CCH*NP;
    #pragma unroll
    for (int s=0;s<16;s++){
      int i = threadIdx.x + s*256;
      int cc = i>>6, pp = i&63;
      size_t g = xbase + (size_t)(c0+cc)*NP + p0+pp;
      float v = isbf ? bf2f(((const bf16*)Xv)[g]) : ((const float*)Xv)[g];
      T[cc][pp] = (short)f2bfbits(v);
    }
    __syncthreads();
    #pragma unroll
    for (int s=0;s<16;s++){
      int i = threadIdx.x + s*256;
      int pl = i>>6, cl = i&63;
      XT[((size_t)b*NP + p0+pl)*CCH + c0+cl] = T[cl][pl];
    }
  } else {
    int i = (blk-384)*256 + threadIdx.x;
    if (i >= NCANON) return;
    const void* src; int off;
    if      (i < 110592){ src = w_qkv;  off = i; }
    else if (i < 111168){ src = b_qkv;  off = i - 110592; }
    else if (i < 116352){ src = w_dw;   off = i - 111168; }
    else if (i < 116928){ src = b_dw;   off = i - 116352; }
    else if (i < 153792){ src = w_proj; off = i - 116928; }
    else if (i < 153984){ src = b_proj; off = i - 153792; }
    else                { src = temp;   off = i - 153984; }
    float v = isbf ? bf2f(((const bf16*)src)[off]) : ((const float*)src)[off];
    canon[i] = __float2bfloat16(v);
  }
}

// ---------------------------------------------------------------------------
// qkv 1x1 conv as MFMA GEMM (bf16 in/out). Block 64o x 128p.
// ---------------------------------------------------------------------------
__global__ __launch_bounds__(256) void qkv_conv_kernel(
    const short* __restrict__ XT, const bf16* __restrict__ Wt,
    const bf16* __restrict__ bias, bf16* __restrict__ Y)
{
  __shared__ __align__(16) short Bs[2][128*32];
  const int tid = threadIdx.x, wave = tid>>6, lane = tid&63;
  const int l16 = lane&15, quad = lane>>4;
  const int o0 = blockIdx.x*64, p0 = blockIdx.y*128, b = blockIdx.z;
  const short* XTb = XT + ((size_t)b*NP + p0)*CCH;
  const short* Wb  = (const short*)Wt;

  f32x4 acc[4][2];
  #pragma unroll
  for (int mt=0;mt<4;mt++){
    #pragma unroll
    for (int r=0;r<4;r++){
      float bv = bf2f(bias[o0+mt*16+quad*4+r]);
      acc[mt][0][r]=bv; acc[mt][1][r]=bv;
    }
  }
  int4 sreg[2];
  I4B8 Afr[2][4];
  #define CLOAD(kc) { _Pragma("unroll") for (int s_=0;s_<2;s_++){ int i_=tid+256*s_; \
      sreg[s_] = *(const int4*)&XTb[(size_t)(i_>>2)*CCH + (kc)*32 + (i_&3)*8]; } }
  #define CSTORE(buf) { _Pragma("unroll") for (int s_=0;s_<2;s_++){ int i_=tid+256*s_; \
      *(int4*)&Bs[buf][(i_>>2)*32 + (i_&3)*8] = sreg[s_]; } }
  #define ALOAD(kc, buf) { _Pragma("unroll") for (int mt_=0;mt_<4;mt_++){ \
      Afr[buf][mt_].i = *(const int4*)&Wb[(size_t)(o0+mt_*16+l16)*CCH + (kc)*32 + quad*8]; } }
  CLOAD(0); CSTORE(0); ALOAD(0,0);
  __syncthreads();
  #pragma unroll
  for (int kc=0; kc<6; kc++){
    const int cur = kc&1;
    if (kc<5){ CLOAD(kc+1); ALOAD(kc+1, cur^1); }
    I4B8 Bf0, Bf1;
    Bf0.i = *(const int4*)&Bs[cur][(wave*32 + l16)*32 + quad*8];
    Bf1.i = *(const int4*)&Bs[cur][(wave*32 + 16 + l16)*32 + quad*8];
    #pragma unroll
    for (int mt=0;mt<4;mt++){
      acc[mt][0] = __builtin_amdgcn_mfma_f32_16x16x32_bf16(Afr[cur][mt].v, Bf0.v, acc[mt][0], 0,0,0);
      acc[mt][1] = __builtin_amdgcn_mfma_f32_16x16x32_bf16(Afr[cur][mt].v, Bf1.v, acc[mt][1], 0,0,0);
    }
    if (kc<5) CSTORE(cur^1);
    __syncthreads();
  }
  #undef CLOAD
  #undef CSTORE
  #undef ALOAD
  #pragma unroll
  for (int mt=0;mt<4;mt++)
    #pragma unroll
    for (int nt=0;nt<2;nt++)
      #pragma unroll
      for (int r=0;r<4;r++){
        int o = o0 + mt*16 + quad*4 + r;
        int p = p0 + wave*32 + nt*16 + l16;
        Y[((size_t)b*C3 + o)*NP + p] = __float2bfloat16(acc[mt][nt][r]);
      }
}

// ---------------------------------------------------------------------------
// 3x3 depthwise conv, padding 1. One block per (b,ch) image.
// ---------------------------------------------------------------------------
__global__ __launch_bounds__(256) void dwconv_kernel(
    const bf16* __restrict__ in, const bf16* __restrict__ w,
    const bf16* __restrict__ bias, bf16* __restrict__ out)
{
  __shared__ __align__(16) short img[4096];
  const int bc = blockIdx.x; const int ch = bc % C3;
  const int tid = threadIdx.x;
  const int4* g4 = (const int4*)(in + (size_t)bc*NP);
  int4* s4 = (int4*)img;
  s4[tid] = g4[tid];
  s4[tid+256] = g4[tid+256];
  float wv[9];
  #pragma unroll
  for (int j=0;j<9;j++) wv[j] = bf2f(w[ch*9+j]);
  const float bv = bf2f(bias[ch]);
  __syncthreads();
  const int y = tid>>2, x0 = (tid&3)*16;
  unsigned outw[8];
  #pragma unroll
  for (int j=0;j<16;j++){
    int x = x0+j;
    float s = bv;
    #pragma unroll
    for (int ky=0;ky<3;ky++){
      int yy = y+ky-1; if (yy<0||yy>63) continue;
      const short* rp = &img[yy<<6];
      #pragma unroll
      for (int kx=0;kx<3;kx++){
        int xx = x+kx-1; if (xx<0||xx>63) continue;
        s += wv[ky*3+kx]*bfb2f(rp[xx]);
      }
    }
    unsigned hb = f2bfbits(s);
    if (j&1) outw[j>>1] |= hb<<16; else outw[j>>1] = hb;
  }
  int4* op = (int4*)((short*)out + (size_t)bc*NP + (y<<6) + x0);
  op[0] = *(int4*)&outw[0];
  op[1] = *(int4*)&outw[4];
}

// ---------------------------------------------------------------------------
// L2 normalize q (in place) and k (-> K^T [bh][n][64], zero-padded d 48..63,
// 16B-unit XOR swizzle by n&7).
// ---------------------------------------------------------------------------
__global__ __launch_bounds__(256) void l2norm_t_kernel(
    bf16* __restrict__ buf, short* __restrict__ KT)
{
  int idx = blockIdx.x*256 + threadIdx.x;   // 65536 total
  int n = idx & 4095; int t = idx >> 12;
  int head = t & 3; int qk = (t>>2)&1; int b = t>>3;
  bf16* p = buf + ((size_t)b*C3 + qk*CCH + head*HD)*NP + n;
  float v[HD];
  float ss = 0.f;
  #pragma unroll
  for (int d=0; d<HD; d++){ v[d] = bf2f(p[(size_t)d*NP]); ss += v[d]*v[d]; }
  float inv = 1.0f / fmaxf(sqrtf(ss), 1e-12f);
  if (qk == 0){
    #pragma unroll
    for (int d=0; d<HD; d++) p[(size_t)d*NP] = __float2bfloat16(v[d]*inv);
  } else {
    short* row = KT + ((size_t)(b*NH+head)*NP + n)*64;
    int sw = n & 7;
    #pragma unroll
    for (int u=0; u<8; u++){
      int4 w = {0,0,0,0};
      if (u < 6){
        int d0 = u*8;
        w.x = pk2(v[d0+0]*inv, v[d0+1]*inv);
        w.y = pk2(v[d0+2]*inv, v[d0+3]*inv);
        w.z = pk2(v[d0+4]*inv, v[d0+5]*inv);
        w.w = pk2(v[d0+6]*inv, v[d0+7]*inv);
      }
      *(int4*)&row[(u^sw)*8] = w;
    }
  }
}

// ---------------------------------------------------------------------------
// Flash attention (R6 form). 512 threads / 8 waves. half = wave>>2 processes
// keys half*2048..+2047 (16 chunks of 128, single-buffered per half);
// wavq = wave&3 owns queries wavq*16..+15 of the 64-query tile.
// S = mfma(A=Q, B=K): lane holds S[query=quad*4+r][key=ct*16+l16].
// Fixed-max softmax (|q.k|<=1): per-ct, no cross-lane ops in loop.
// P via per-wave LDS (16x68, conflict-free banks), half-width double-pump.
// Halves combine through LDS at the end. Writes OT [b][n][192] bf16.
// ---------------------------------------------------------------------------
__global__ __launch_bounds__(512) void flash_kernel(
    const bf16* __restrict__ qkv,      // bufB [b][c3][n]
    const short* __restrict__ KT,      // [bh][n][64] swizzled bf16 bits
    const bf16* __restrict__ temp,
    short* __restrict__ OT)            // [b][4096][192] bf16 bits
{
  __shared__ __align__(16) short Ks[2][128*64];   // per-half, 16 KB each
  __shared__ __align__(16) short Vs[2][48*136];   // per-half, 13056 each
  __shared__ __align__(16) short Ps[8][16*68];    // per-wave, 2176 each

  const int bh = blockIdx.x, b = bh>>2, head = bh&3;
  const int q0 = blockIdx.y * 64;
  const int tid = threadIdx.x;
  const int wave = tid>>6, lane = tid&63;
  const int half = wave>>2, wavq = wave&3;
  const int l16 = lane&15, quad = lane>>4;
  const int t256 = tid & 255;

  const unsigned short* Qp = (const unsigned short*)(qkv + ((size_t)b*C3 + head*HD)*NP)
                             + q0 + wavq*16 + l16;
  const short* Vp = (const short*)(qkv + ((size_t)b*C3 + 2*CCH + head*HD)*NP);
  const short* KTs = KT + (size_t)bh*NP*64;
  const float sc = bf2f(temp[head]) * 1.44269504f;
  const float negM = -__builtin_fabsf(sc);
  const int kbase = half*2048;

  // Q A-fragments: A[m=query l16][k=d quad*8+j]; aq1 covers d 32..63 (pad>47=0)
  I4B8 aq0, aq1;
  {
    unsigned qb[8];
    #pragma unroll
    for (int j=0;j<8;j++) qb[j] = Qp[(size_t)(quad*8+j)*NP];
    aq0.i.x = qb[0]|(qb[1]<<16); aq0.i.y = qb[2]|(qb[3]<<16);
    aq0.i.z = qb[4]|(qb[5]<<16); aq0.i.w = qb[6]|(qb[7]<<16);
    if (quad < 2){
      #pragma unroll
      for (int j=0;j<8;j++) qb[j] = Qp[(size_t)(32+quad*8+j)*NP];
      aq1.i.x = qb[0]|(qb[1]<<16); aq1.i.y = qb[2]|(qb[3]<<16);
      aq1.i.z = qb[4]|(qb[5]<<16); aq1.i.w = qb[6]|(qb[7]<<16);
    } else { aq1.i.x=0; aq1.i.y=0; aq1.i.z=0; aq1.i.w=0; }
  }

  f32x4 O0 = {0,0,0,0}, O1 = {0,0,0,0}, O2 = {0,0,0,0};
  float rs[4] = {0.f,0.f,0.f,0.f};
  short* Pw = Ps[wave];
  const int sw = l16 & 7;

  int4 kreg[4], vreg[3];
  #define KLOAD(T) { const int k0_ = kbase + ((T)<<7); \
    const int4* gk_ = (const int4*)(KTs + (size_t)k0_*64); \
    _Pragma("unroll") for (int s_=0;s_<4;s_++) kreg[s_] = gk_[t256 + 256*s_]; \
    _Pragma("unroll") for (int s_=0;s_<3;s_++){ int i_=t256+256*s_; \
      vreg[s_] = *(const int4*)(Vp + (size_t)(i_>>4)*NP + k0_ + (i_&15)*8); } }
  #define KSTORE { int4* lk_ = (int4*)&Ks[half][0]; \
    _Pragma("unroll") for (int s_=0;s_<4;s_++) lk_[t256+256*s_] = kreg[s_]; \
    _Pragma("unroll") for (int s_=0;s_<3;s_++){ int i_=t256+256*s_; \
      *(int4*)&Vs[half][(i_>>4)*136 + (i_&15)*8] = vreg[s_]; } }

  KLOAD(0); KSTORE;
  __syncthreads();

  for (int t=0; t<16; ++t){
    if (t < 15) KLOAD(t+1);

    const short* Kb = &Ks[half][0];
    const short* Vb = &Vs[half][0];

    // two half-chunks of 64 keys; P half-width (16x68) per wave
    #pragma unroll
    for (int hc=0; hc<2; ++hc){
      #pragma unroll
      for (int c4=0; c4<4; ++c4){
        const int ct = hc*4 + c4;
        const int row = (ct*16 + l16)*64;
        I4B8 bk0, bk1;
        bk0.i = *(const int4*)&Kb[row + ((quad^sw)*8)];
        bk1.i = *(const int4*)&Kb[row + (((4+quad)^sw)*8)];
        f32x4 s = {0,0,0,0};
        s = __builtin_amdgcn_mfma_f32_16x16x32_bf16(aq0.v, bk0.v, s, 0,0,0);
        s = __builtin_amdgcn_mfma_f32_16x16x32_bf16(aq1.v, bk1.v, s, 0,0,0);
        #pragma unroll
        for (int r=0;r<4;r++){
          float p = __builtin_amdgcn_exp2f(__builtin_fmaf(s[r], sc, negM));
          rs[r] += p;
          Pw[(quad*4+r)*68 + c4*16 + l16] = (short)f2bfbits(p);
        }
      }
      // O += P V for these 64 keys (wave-private Ps; lgkm orders wr->rd)
      #pragma unroll
      for (int c=0;c<2;c++){
        I4B8 AP, BV0, BV1, BV2;
        AP.i  = *(const int4*)&Pw[l16*68 + c*32 + quad*8];
        BV0.i = *(const int4*)&Vb[(l16   )*136 + hc*64 + c*32 + quad*8];
        BV1.i = *(const int4*)&Vb[(16+l16)*136 + hc*64 + c*32 + quad*8];
        BV2.i = *(const int4*)&Vb[(32+l16)*136 + hc*64 + c*32 + quad*8];
        O0 = __builtin_amdgcn_mfma_f32_16x16x32_bf16(AP.v, BV0.v, O0, 0,0,0);
        O1 = __builtin_amdgcn_mfma_f32_16x16x32_bf16(AP.v, BV1.v, O1, 0,0,0);
        O2 = __builtin_amdgcn_mfma_f32_16x16x32_bf16(AP.v, BV2.v, O2, 0,0,0);
      }
    }

    if (t < 15){
      __syncthreads();   // all waves done reading this half's Ks/Vs
      KSTORE;
      __syncthreads();   // new tiles visible
    }
  }
  #undef KLOAD
  #undef KSTORE

  // l per query row (this half): reduce over the 16 key-lanes
  #pragma unroll
  for (int r=0;r<4;r++){
    float v = rs[r];
    v += __shfl_xor(v,1); v += __shfl_xor(v,2);
    v += __shfl_xor(v,4); v += __shfl_xor(v,8);
    rs[r] = v;
  }

  // combine halves through LDS (reuse Ks[0]: 64 q x 52 floats = 13312 B)
  __syncthreads();
  float* Cb = (float*)&Ks[0][0];
  if (half == 1){
    #pragma unroll
    for (int r=0;r<4;r++){
      int q = wavq*16 + quad*4 + r;
      float* dst = Cb + q*52;
      dst[l16]    = O0[r];
      dst[16+l16] = O1[r];
      dst[32+l16] = O2[r];
      if (l16 == 0) dst[48] = rs[r];
    }
  }
  __syncthreads();
  if (half == 0){
    #pragma unroll
    for (int r=0;r<4;r++){
      int q = wavq*16 + quad*4 + r;
      const float* src = Cb + q*52;
      float invl = 1.0f / (rs[r] + src[48]);
      short* row = OT + ((size_t)b*NP + q0 + q)*CCH + head*HD;
      row[l16]    = (short)f2bfbits((O0[r]+src[l16])*invl);
      row[16+l16] = (short)f2bfbits((O1[r]+src[16+l16])*invl);
      row[32+l16] = (short)f2bfbits((O2[r]+src[32+l16])*invl);
    }
  }
}

// ---------------------------------------------------------------------------
// Proj conv (MFMA): 64o x 64p blocks (384 total). Output dtype inline-probed.
// ---------------------------------------------------------------------------
__global__ __launch_bounds__(256) void proj_kernel(
    const void* __restrict__ Xprobe,
    const short* __restrict__ OT, const bf16* __restrict__ Wt,
    const bf16* __restrict__ bias, void* __restrict__ Yv)
{
  const bool yf32 = !probe64(Xprobe);
  __shared__ __align__(16) short Bs[2][64*32];
  const int tid = threadIdx.x, wave = tid>>6, lane = tid&63;
  const int l16 = lane&15, quad = lane>>4;
  const int o0 = blockIdx.x*64, p0 = blockIdx.y*64, b = blockIdx.z;
  const short* XTb = OT + ((size_t)b*NP + p0)*CCH;
  const short* Wb  = (const short*)Wt;
  f32x4 acc[4];
  #pragma unroll
  for (int mt=0;mt<4;mt++)
    #pragma unroll
    for (int r=0;r<4;r++)
      acc[mt][r] = bf2f(bias[o0+mt*16+quad*4+r]);

  int4 sreg;
  I4B8 Afr[2][4];
  #define CLOAD(kc) { sreg = *(const int4*)&XTb[(size_t)(tid>>2)*CCH + (kc)*32 + (tid&3)*8]; }
  #define CSTORE(buf) { *(int4*)&Bs[buf][(tid>>2)*32 + (tid&3)*8] = sreg; }
  #define ALOAD(kc, buf) { _Pragma("unroll") for (int mt_=0;mt_<4;mt_++){ \
      Afr[buf][mt_].i = *(const int4*)&Wb[(size_t)(o0+mt_*16+l16)*CCH + (kc)*32 + quad*8]; } }
  CLOAD(0); CSTORE(0); ALOAD(0,0);
  __syncthreads();
  #pragma unroll
  for (int kc=0; kc<6; kc++){
    const int cur = kc&1;
    if (kc<5){ CLOAD(kc+1); ALOAD(kc+1, cur^1); }
    I4B8 Bf;
    Bf.i = *(const int4*)&Bs[cur][(wave*16 + l16)*32 + quad*8];
    #pragma unroll
    for (int mt=0;mt<4;mt++)
      acc[mt] = __builtin_amdgcn_mfma_f32_16x16x32_bf16(Afr[cur][mt].v, Bf.v, acc[mt], 0,0,0);
    if (kc<5) CSTORE(cur^1);
    __syncthreads();
  }
  #undef CLOAD
  #undef CSTORE
  #undef ALOAD
  #pragma unroll
  for (int mt=0;mt<4;mt++)
    #pragma unroll
    for (int r=0;r<4;r++){
      int o = o0 + mt*16 + quad*4 + r;
      int p = p0 + wave*16 + l16;
      size_t off = ((size_t)b*CCH + o)*NP + p;
      if (yf32) ((float*)Yv)[off] = acc[mt][r];
      else      ((bf16*)Yv)[off]  = __float2bfloat16(acc[mt][r]);
    }
}

// ---------------------------------------------------------------------------
extern "C" void kernel_launch(void* const* d_in, const int* in_sizes, int n_in,
                              void* d_out, int out_size, void* d_ws, size_t ws_size,
                              hipStream_t stream)
{
  // ws layout (bytes) — 19.2 MB footprint proven since R3:
  //   [16]        bf16 canon[153988]
  //   [308096]    bf16 bufA[2*576*4096]  (OT head; K^T at el 1572864)
  //   [9745280]   bf16 bufB[2*576*4096]  (X^T borrows head pre-dwconv)
  bf16* canon = (bf16*)((char*)d_ws + 16);
  bf16* bufA  = (bf16*)((char*)d_ws + 308096);
  bf16* bufB  = (bf16*)((char*)d_ws + 9745280);
  short* XT = (short*)bufB;
  short* OT = (short*)bufA;
  short* KT = (short*)(bufA + 1572864);

  bf16* cw_qkv  = canon;
  bf16* cb_qkv  = canon + 110592;
  bf16* cw_dw   = canon + 111168;
  bf16* cb_dw   = canon + 116352;
  bf16* cw_proj = canon + 116928;
  bf16* cb_proj = canon + 153792;
  bf16* ctemp   = canon + 153984;

  pre_kernel<<<986, 256, 0, stream>>>(d_in[0],
      d_in[1], d_in[2], d_in[3], d_in[4], d_in[5], d_in[6], d_in[7],
      canon, XT);
  qkv_conv_kernel<<<dim3(9,32,2), 256, 0, stream>>>(XT, cw_qkv, cb_qkv, bufA);
  dwconv_kernel<<<dim3(BB*C3), 256, 0, stream>>>(bufA, cw_dw, cb_dw, bufB);
  l2norm_t_kernel<<<dim3(256), 256, 0, stream>>>(bufB, KT);
  flash_kernel<<<dim3(8,64), 512, 0, stream>>>(bufB, KT, ctemp, OT);
  proj_kernel<<<dim3(3,64,2), 256, 0, stream>>>(d_in[0],
      OT, cw_proj, cb_proj, d_out);
}

// Round 11
// 220.955 us; speedup vs baseline: 1.2519x; 1.2519x over previous
//
#include <hip/hip_runtime.h>
#include <hip/hip_bf16.h>

// MDTA: [convert+transpose fused] -> qkv 1x1 conv (MFMA) -> 3x3 depthwise ->
// l2norm(q)+K^T materialize -> flash attention (R6 dbuf form) -> proj (MFMA).
//
// HARD-WON LESSON (R7-R10): if the global->reg prefetch registers (kreg/vreg)
// must stay live ACROSS a __syncthreads() (single-buffer form: load, barrier,
// store), the allocator demotes them to scratch: VGPR_Count drops to ~56 and
// 200-450 MB of HBM scratch writes appear (112 B/thread/iter). The R6 form
// (double-buffered LDS, KSTORE *before* the single barrier, prefetch regs
// dead at the barrier) allocates ~104 VGPRs and writes 3 MB. KEEP THE R6
// FORM. Only localized change vs R6: Ps pitch 136 -> 68 (two-pump), which
// makes P-writes bank-disjoint per quad (was 4-way conflicting).

#define BB 2
#define CCH 192
#define C3 576
#define NH 4
#define HD 48
#define NP 4096

typedef __hip_bfloat16 bf16;
typedef __attribute__((ext_vector_type(8))) short bf16x8;
typedef __attribute__((ext_vector_type(4))) float f32x4;

union I4B8 { int4 i; bf16x8 v; };

__device__ inline float bf2f(bf16 v){ return __bfloat162float(v); }
__device__ inline unsigned short bfbits(bf16 v){ return __builtin_bit_cast(unsigned short, v); }
__device__ inline unsigned short f2bfbits(float f){ return __builtin_bit_cast(unsigned short, __float2bfloat16(f)); }
__device__ inline float bfb2f(short s){ return __uint_as_float(((unsigned)(unsigned short)s)<<16); }
__device__ inline unsigned pk2(float a, float b){
  return (unsigned)f2bfbits(a) | ((unsigned)f2bfbits(b)<<16);
}

// Inline dtype probe: bf16 data -> low short of dwords has sane exponent.
__device__ inline bool probe64(const void* x){
  unsigned u = ((const unsigned*)x)[threadIdx.x & 63];
  int e = (u >> 7) & 0xff;
  int sane = (e >= 100 && e <= 140) || ((u & 0x7fffu) == 0u);
  unsigned long long m = __ballot(sane);
  return __popcll(m) >= 48;
}

// ---------------------------------------------------------------------------
// Fused: blocks 0..383 transpose X -> XT [b][4096][192] bf16; blocks
// 384..985 convert params to canonical bf16.
// ---------------------------------------------------------------------------
#define NCANON 153988
__global__ __launch_bounds__(256) void pre_kernel(
    const void* __restrict__ Xv,
    const void* w_qkv, const void* b_qkv, const void* w_dw, const void* b_dw,
    const void* w_proj, const void* b_proj, const void* temp,
    bf16* __restrict__ canon, short* __restrict__ XT)
{
  const bool isbf = probe64(Xv);
  const int blk = blockIdx.x;
  if (blk < 384){
    __shared__ short T[64][66];
    const int c0 = (blk % 3)*64, p0 = ((blk/3) % 64)*64, b = blk/192;
    const size_t xbase = (size_t)b*CCH*NP;
    #pragma unroll
    for (int s=0;s<16;s++){
      int i = threadIdx.x + s*256;
      int cc = i>>6, pp = i&63;
      size_t g = xbase + (size_t)(c0+cc)*NP + p0+pp;
      float v = isbf ? bf2f(((const bf16*)Xv)[g]) : ((const float*)Xv)[g];
      T[cc][pp] = (short)f2bfbits(v);
    }
    __syncthreads();
    #pragma unroll
    for (int s=0;s<16;s++){
      int i = threadIdx.x + s*256;
      int pl = i>>6, cl = i&63;
      XT[((size_t)b*NP + p0+pl)*CCH + c0+cl] = T[cl][pl];
    }
  } else {
    int i = (blk-384)*256 + threadIdx.x;
    if (i >= NCANON) return;
    const void* src; int off;
    if      (i < 110592){ src = w_qkv;  off = i; }
    else if (i < 111168){ src = b_qkv;  off = i - 110592; }
    else if (i < 116352){ src = w_dw;   off = i - 111168; }
    else if (i < 116928){ src = b_dw;   off = i - 116352; }
    else if (i < 153792){ src = w_proj; off = i - 116928; }
    else if (i < 153984){ src = b_proj; off = i - 153792; }
    else                { src = temp;   off = i - 153984; }
    float v = isbf ? bf2f(((const bf16*)src)[off]) : ((const float*)src)[off];
    canon[i] = __float2bfloat16(v);
  }
}

// ---------------------------------------------------------------------------
// qkv 1x1 conv as MFMA GEMM (bf16 in/out). Block 64o x 128p.
// ---------------------------------------------------------------------------
__global__ __launch_bounds__(256) void qkv_conv_kernel(
    const short* __restrict__ XT, const bf16* __restrict__ Wt,
    const bf16* __restrict__ bias, bf16* __restrict__ Y)
{
  __shared__ __align__(16) short Bs[2][128*32];
  const int tid = threadIdx.x, wave = tid>>6, lane = tid&63;
  const int l16 = lane&15, quad = lane>>4;
  const int o0 = blockIdx.x*64, p0 = blockIdx.y*128, b = blockIdx.z;
  const short* XTb = XT + ((size_t)b*NP + p0)*CCH;
  const short* Wb  = (const short*)Wt;

  f32x4 acc[4][2];
  #pragma unroll
  for (int mt=0;mt<4;mt++){
    #pragma unroll
    for (int r=0;r<4;r++){
      float bv = bf2f(bias[o0+mt*16+quad*4+r]);
      acc[mt][0][r]=bv; acc[mt][1][r]=bv;
    }
  }
  int4 sreg[2];
  I4B8 Afr[2][4];
  #define CLOAD(kc) { _Pragma("unroll") for (int s_=0;s_<2;s_++){ int i_=tid+256*s_; \
      sreg[s_] = *(const int4*)&XTb[(size_t)(i_>>2)*CCH + (kc)*32 + (i_&3)*8]; } }
  #define CSTORE(buf) { _Pragma("unroll") for (int s_=0;s_<2;s_++){ int i_=tid+256*s_; \
      *(int4*)&Bs[buf][(i_>>2)*32 + (i_&3)*8] = sreg[s_]; } }
  #define ALOAD(kc, buf) { _Pragma("unroll") for (int mt_=0;mt_<4;mt_++){ \
      Afr[buf][mt_].i = *(const int4*)&Wb[(size_t)(o0+mt_*16+l16)*CCH + (kc)*32 + quad*8]; } }
  CLOAD(0); CSTORE(0); ALOAD(0,0);
  __syncthreads();
  #pragma unroll
  for (int kc=0; kc<6; kc++){
    const int cur = kc&1;
    if (kc<5){ CLOAD(kc+1); ALOAD(kc+1, cur^1); }
    I4B8 Bf0, Bf1;
    Bf0.i = *(const int4*)&Bs[cur][(wave*32 + l16)*32 + quad*8];
    Bf1.i = *(const int4*)&Bs[cur][(wave*32 + 16 + l16)*32 + quad*8];
    #pragma unroll
    for (int mt=0;mt<4;mt++){
      acc[mt][0] = __builtin_amdgcn_mfma_f32_16x16x32_bf16(Afr[cur][mt].v, Bf0.v, acc[mt][0], 0,0,0);
      acc[mt][1] = __builtin_amdgcn_mfma_f32_16x16x32_bf16(Afr[cur][mt].v, Bf1.v, acc[mt][1], 0,0,0);
    }
    if (kc<5) CSTORE(cur^1);
    __syncthreads();
  }
  #undef CLOAD
  #undef CSTORE
  #undef ALOAD
  #pragma unroll
  for (int mt=0;mt<4;mt++)
    #pragma unroll
    for (int nt=0;nt<2;nt++)
      #pragma unroll
      for (int r=0;r<4;r++){
        int o = o0 + mt*16 + quad*4 + r;
        int p = p0 + wave*32 + nt*16 + l16;
        Y[((size_t)b*C3 + o)*NP + p] = __float2bfloat16(acc[mt][nt][r]);
      }
}

// ---------------------------------------------------------------------------
// 3x3 depthwise conv, padding 1. One block per (b,ch) image.
// ---------------------------------------------------------------------------
__global__ __launch_bounds__(256) void dwconv_kernel(
    const bf16* __restrict__ in, const bf16* __restrict__ w,
    const bf16* __restrict__ bias, bf16* __restrict__ out)
{
  __shared__ __align__(16) short img[4096];
  const int bc = blockIdx.x; const int ch = bc % C3;
  const int tid = threadIdx.x;
  const int4* g4 = (const int4*)(in + (size_t)bc*NP);
  int4* s4 = (int4*)img;
  s4[tid] = g4[tid];
  s4[tid+256] = g4[tid+256];
  float wv[9];
  #pragma unroll
  for (int j=0;j<9;j++) wv[j] = bf2f(w[ch*9+j]);
  const float bv = bf2f(bias[ch]);
  __syncthreads();
  const int y = tid>>2, x0 = (tid&3)*16;
  unsigned outw[8];
  #pragma unroll
  for (int j=0;j<16;j++){
    int x = x0+j;
    float s = bv;
    #pragma unroll
    for (int ky=0;ky<3;ky++){
      int yy = y+ky-1; if (yy<0||yy>63) continue;
      const short* rp = &img[yy<<6];
      #pragma unroll
      for (int kx=0;kx<3;kx++){
        int xx = x+kx-1; if (xx<0||xx>63) continue;
        s += wv[ky*3+kx]*bfb2f(rp[xx]);
      }
    }
    unsigned hb = f2bfbits(s);
    if (j&1) outw[j>>1] |= hb<<16; else outw[j>>1] = hb;
  }
  int4* op = (int4*)((short*)out + (size_t)bc*NP + (y<<6) + x0);
  op[0] = *(int4*)&outw[0];
  op[1] = *(int4*)&outw[4];
}

// ---------------------------------------------------------------------------
// L2 normalize q (in place) and k (-> K^T [bh][n][64], zero-padded d 48..63,
// 16B-unit XOR swizzle by n&7).
// ---------------------------------------------------------------------------
__global__ __launch_bounds__(256) void l2norm_t_kernel(
    bf16* __restrict__ buf, short* __restrict__ KT)
{
  int idx = blockIdx.x*256 + threadIdx.x;   // 65536 total
  int n = idx & 4095; int t = idx >> 12;
  int head = t & 3; int qk = (t>>2)&1; int b = t>>3;
  bf16* p = buf + ((size_t)b*C3 + qk*CCH + head*HD)*NP + n;
  float v[HD];
  float ss = 0.f;
  #pragma unroll
  for (int d=0; d<HD; d++){ v[d] = bf2f(p[(size_t)d*NP]); ss += v[d]*v[d]; }
  float inv = 1.0f / fmaxf(sqrtf(ss), 1e-12f);
  if (qk == 0){
    #pragma unroll
    for (int d=0; d<HD; d++) p[(size_t)d*NP] = __float2bfloat16(v[d]*inv);
  } else {
    short* row = KT + ((size_t)(b*NH+head)*NP + n)*64;
    int sw = n & 7;
    #pragma unroll
    for (int u=0; u<8; u++){
      int4 w = {0,0,0,0};
      if (u < 6){
        int d0 = u*8;
        w.x = pk2(v[d0+0]*inv, v[d0+1]*inv);
        w.y = pk2(v[d0+2]*inv, v[d0+3]*inv);
        w.z = pk2(v[d0+4]*inv, v[d0+5]*inv);
        w.w = pk2(v[d0+6]*inv, v[d0+7]*inv);
      }
      *(int4*)&row[(u^sw)*8] = w;
    }
  }
}

// ---------------------------------------------------------------------------
// Flash attention — EXACT R6 structure: 256 threads / 4 waves, K chunk 128,
// double-buffered Ks/Vs, KLOAD at loop top, KSTORE before the single
// barrier (prefetch regs dead at the barrier -> no spill). Fixed-max
// softmax (|q.k|<=1): no in-loop cross-lane ops. Only change vs R6:
// Ps pitch 68 + two-pump (bank-disjoint P writes). Writes OT [b][n][192].
// ---------------------------------------------------------------------------
__global__ __launch_bounds__(256) void flash_kernel(
    const bf16* __restrict__ qkv,      // bufB [b][c3][n]
    const short* __restrict__ KT,      // [bh][n][64] swizzled bf16 bits
    const bf16* __restrict__ temp,
    short* __restrict__ OT)            // [b][4096][192] bf16 bits
{
  __shared__ __align__(16) short Ks[2][128*64];   // 32 KB
  __shared__ __align__(16) short Vs[2][48*136];   // 26112 B
  __shared__ __align__(16) short Ps[4][16*68];    // 8704 B (pitch 68)

  const int bh = blockIdx.x, b = bh>>2, head = bh&3;
  const int q0 = blockIdx.y * 64;
  const int tid = threadIdx.x, wave = tid>>6, lane = tid&63;
  const int l16 = lane&15, quad = lane>>4;

  const unsigned short* Qp = (const unsigned short*)(qkv + ((size_t)b*C3 + head*HD)*NP)
                             + q0 + wave*16 + l16;
  const short* Vp = (const short*)(qkv + ((size_t)b*C3 + 2*CCH + head*HD)*NP);
  const short* KTs = KT + (size_t)bh*NP*64;
  const float sc = bf2f(temp[head]) * 1.44269504f;
  const float negM = -__builtin_fabsf(sc);       // fixed softmax shift

  // Q A-fragments: A[m=query l16][k=d quad*8+j]; aq1 covers d 32..63 (pad=0)
  I4B8 aq0, aq1;
  {
    unsigned qb[8];
    #pragma unroll
    for (int j=0;j<8;j++) qb[j] = Qp[(size_t)(quad*8+j)*NP];
    aq0.i.x = qb[0]|(qb[1]<<16); aq0.i.y = qb[2]|(qb[3]<<16);
    aq0.i.z = qb[4]|(qb[5]<<16); aq0.i.w = qb[6]|(qb[7]<<16);
    if (quad < 2){
      #pragma unroll
      for (int j=0;j<8;j++) qb[j] = Qp[(size_t)(32+quad*8+j)*NP];
      aq1.i.x = qb[0]|(qb[1]<<16); aq1.i.y = qb[2]|(qb[3]<<16);
      aq1.i.z = qb[4]|(qb[5]<<16); aq1.i.w = qb[6]|(qb[7]<<16);
    } else { aq1.i.x=0; aq1.i.y=0; aq1.i.z=0; aq1.i.w=0; }
  }

  f32x4 O0 = {0,0,0,0}, O1 = {0,0,0,0}, O2 = {0,0,0,0};
  float rs[4] = {0.f, 0.f, 0.f, 0.f};   // per-lane partial row sums
  short* Pw = Ps[wave];
  const int sw = l16 & 7;

  int4 kreg[4], vreg[3];
  #define KLOAD(CHUNK) { const int k0_=(CHUNK)<<7; \
    const int4* gk_ = (const int4*)(KTs + (size_t)k0_*64); \
    _Pragma("unroll") for (int s_=0;s_<4;s_++) kreg[s_] = gk_[tid + 256*s_]; \
    _Pragma("unroll") for (int s_=0;s_<3;s_++){ int i_=tid+256*s_; \
      vreg[s_] = *(const int4*)(Vp + (size_t)(i_>>4)*NP + k0_ + (i_&15)*8); } }
  #define KSTORE(BUFI) { int4* lk_ = (int4*)&Ks[BUFI][0]; \
    _Pragma("unroll") for (int s_=0;s_<4;s_++) lk_[tid+256*s_] = kreg[s_]; \
    _Pragma("unroll") for (int s_=0;s_<3;s_++){ int i_=tid+256*s_; \
      *(int4*)&Vs[BUFI][(i_>>4)*136 + (i_&15)*8] = vreg[s_]; } }

  KLOAD(0); KSTORE(0);
  __syncthreads();

  for (int t=0; t<32; ++t){
    const int cur = t & 1;
    if (t < 31) KLOAD(t+1);

    const short* Kb = &Ks[cur][0];
    const short* Vb = &Vs[cur][0];

    // two pumps of 64 keys; Ps is 16x68 per wave (bank-disjoint per quad)
    #pragma unroll
    for (int hc=0; hc<2; ++hc){
      #pragma unroll
      for (int c4=0; c4<4; ++c4){
        const int ct = hc*4 + c4;
        const int row = (ct*16 + l16)*64;
        I4B8 bk0, bk1;
        bk0.i = *(const int4*)&Kb[row + ((quad^sw)*8)];
        bk1.i = *(const int4*)&Kb[row + (((4+quad)^sw)*8)];
        f32x4 s = {0,0,0,0};
        s = __builtin_amdgcn_mfma_f32_16x16x32_bf16(aq0.v, bk0.v, s, 0,0,0);
        s = __builtin_amdgcn_mfma_f32_16x16x32_bf16(aq1.v, bk1.v, s, 0,0,0);
        #pragma unroll
        for (int r=0;r<4;r++){
          float p = __builtin_amdgcn_exp2f(__builtin_fmaf(s[r], sc, negM));
          rs[r] += p;
          Pw[(quad*4+r)*68 + c4*16 + l16] = (short)f2bfbits(p);
        }
      }
      // O += P V for these 64 keys (wave-private Ps; lgkm orders wr->rd)
      #pragma unroll
      for (int c=0;c<2;c++){
        I4B8 AP, BV0, BV1, BV2;
        AP.i  = *(const int4*)&Pw[l16*68 + c*32 + quad*8];
        BV0.i = *(const int4*)&Vb[(l16   )*136 + hc*64 + c*32 + quad*8];
        BV1.i = *(const int4*)&Vb[(16+l16)*136 + hc*64 + c*32 + quad*8];
        BV2.i = *(const int4*)&Vb[(32+l16)*136 + hc*64 + c*32 + quad*8];
        O0 = __builtin_amdgcn_mfma_f32_16x16x32_bf16(AP.v, BV0.v, O0, 0,0,0);
        O1 = __builtin_amdgcn_mfma_f32_16x16x32_bf16(AP.v, BV1.v, O1, 0,0,0);
        O2 = __builtin_amdgcn_mfma_f32_16x16x32_bf16(AP.v, BV2.v, O2, 0,0,0);
      }
    }

    if (t < 31) KSTORE(cur^1);   // prefetch regs die HERE, before the barrier
    __syncthreads();
  }
  #undef KLOAD
  #undef KSTORE

  // l per query row: reduce over the 16 key-lanes (once, after the loop)
  float l[4];
  #pragma unroll
  for (int r=0;r<4;r++){
    float v = rs[r];
    v += __shfl_xor(v,1); v += __shfl_xor(v,2);
    v += __shfl_xor(v,4); v += __shfl_xor(v,8);
    l[r] = v;
  }

  // O^T epilogue: row = query position, cols = head*48 + d
  #pragma unroll
  for (int r=0;r<4;r++){
    float invl = 1.0f / l[r];
    short* row = OT + ((size_t)b*NP + q0 + wave*16 + quad*4 + r)*CCH + head*HD;
    row[l16]    = (short)f2bfbits(O0[r]*invl);
    row[16+l16] = (short)f2bfbits(O1[r]*invl);
    row[32+l16] = (short)f2bfbits(O2[r]*invl);
  }
}

// ---------------------------------------------------------------------------
// Proj conv (MFMA): 64o x 64p blocks (384 total). Output dtype inline-probed.
// ---------------------------------------------------------------------------
__global__ __launch_bounds__(256) void proj_kernel(
    const void* __restrict__ Xprobe,
    const short* __restrict__ OT, const bf16* __restrict__ Wt,
    const bf16* __restrict__ bias, void* __restrict__ Yv)
{
  const bool yf32 = !probe64(Xprobe);
  __shared__ __align__(16) short Bs[2][64*32];
  const int tid = threadIdx.x, wave = tid>>6, lane = tid&63;
  const int l16 = lane&15, quad = lane>>4;
  const int o0 = blockIdx.x*64, p0 = blockIdx.y*64, b = blockIdx.z;
  const short* XTb = OT + ((size_t)b*NP + p0)*CCH;
  const short* Wb  = (const short*)Wt;
  f32x4 acc[4];
  #pragma unroll
  for (int mt=0;mt<4;mt++)
    #pragma unroll
    for (int r=0;r<4;r++)
      acc[mt][r] = bf2f(bias[o0+mt*16+quad*4+r]);

  int4 sreg;
  I4B8 Afr[2][4];
  #define CLOAD(kc) { sreg = *(const int4*)&XTb[(size_t)(tid>>2)*CCH + (kc)*32 + (tid&3)*8]; }
  #define CSTORE(buf) { *(int4*)&Bs[buf][(tid>>2)*32 + (tid&3)*8] = sreg; }
  #define ALOAD(kc, buf) { _Pragma("unroll") for (int mt_=0;mt_<4;mt_++){ \
      Afr[buf][mt_].i = *(const int4*)&Wb[(size_t)(o0+mt_*16+l16)*CCH + (kc)*32 + quad*8]; } }
  CLOAD(0); CSTORE(0); ALOAD(0,0);
  __syncthreads();
  #pragma unroll
  for (int kc=0; kc<6; kc++){
    const int cur = kc&1;
    if (kc<5){ CLOAD(kc+1); ALOAD(kc+1, cur^1); }
    I4B8 Bf;
    Bf.i = *(const int4*)&Bs[cur][(wave*16 + l16)*32 + quad*8];
    #pragma unroll
    for (int mt=0;mt<4;mt++)
      acc[mt] = __builtin_amdgcn_mfma_f32_16x16x32_bf16(Afr[cur][mt].v, Bf.v, acc[mt], 0,0,0);
    if (kc<5) CSTORE(cur^1);
    __syncthreads();
  }
  #undef CLOAD
  #undef CSTORE
  #undef ALOAD
  #pragma unroll
  for (int mt=0;mt<4;mt++)
    #pragma unroll
    for (int r=0;r<4;r++){
      int o = o0 + mt*16 + quad*4 + r;
      int p = p0 + wave*16 + l16;
      size_t off = ((size_t)b*CCH + o)*NP + p;
      if (yf32) ((float*)Yv)[off] = acc[mt][r];
      else      ((bf16*)Yv)[off]  = __float2bfloat16(acc[mt][r]);
    }
}

// ---------------------------------------------------------------------------
extern "C" void kernel_launch(void* const* d_in, const int* in_sizes, int n_in,
                              void* d_out, int out_size, void* d_ws, size_t ws_size,
                              hipStream_t stream)
{
  // ws layout (bytes) — 19.2 MB footprint proven since R3:
  //   [16]        bf16 canon[153988]
  //   [308096]    bf16 bufA[2*576*4096]  (OT head; K^T at el 1572864)
  //   [9745280]   bf16 bufB[2*576*4096]  (X^T borrows head pre-dwconv)
  bf16* canon = (bf16*)((char*)d_ws + 16);
  bf16* bufA  = (bf16*)((char*)d_ws + 308096);
  bf16* bufB  = (bf16*)((char*)d_ws + 9745280);
  short* XT = (short*)bufB;
  short* OT = (short*)bufA;
  short* KT = (short*)(bufA + 1572864);

  bf16* cw_qkv  = canon;
  bf16* cb_qkv  = canon + 110592;
  bf16* cw_dw   = canon + 111168;
  bf16* cb_dw   = canon + 116352;
  bf16* cw_proj = canon + 116928;
  bf16* cb_proj = canon + 153792;
  bf16* ctemp   = canon + 153984;

  pre_kernel<<<986, 256, 0, stream>>>(d_in[0],
      d_in[1], d_in[2], d_in[3], d_in[4], d_in[5], d_in[6], d_in[7],
      canon, XT);
  qkv_conv_kernel<<<dim3(9,32,2), 256, 0, stream>>>(XT, cw_qkv, cb_qkv, bufA);
  dwconv_kernel<<<dim3(BB*C3), 256, 0, stream>>>(bufA, cw_dw, cb_dw, bufB);
  l2norm_t_kernel<<<dim3(256), 256, 0, stream>>>(bufB, KT);
  flash_kernel<<<dim3(8,64), 256, 0, stream>>>(bufB, KT, ctemp, OT);
  proj_kernel<<<dim3(3,64,2), 256, 0, stream>>>(d_in[0],
      OT, cw_proj, cb_proj, d_out);
}